// Round 4
// baseline (309.056 us; speedup 1.0000x reference)
//
#include <hip/hip_runtime.h>

// Problem: B=4, S=2048, D=1024, H=16, HD=64.
#define NB 4
#define NS 2048
#define ND 1024
#define NH 16
#define NE 64
#define NM (NB*NS)   // 8192 rows

typedef __attribute__((ext_vector_type(8))) __bf16 bf16x8;           // MFMA A/B frag (4 VGPRs)
typedef __attribute__((ext_vector_type(4))) float f32x4;             // MFMA C/D frag

__device__ __forceinline__ float bf2f(unsigned short h) {
  union { unsigned u; float f; } c; c.u = ((unsigned)h) << 16; return c.f;
}
__device__ __forceinline__ unsigned short f2bf(float f) {
  union { float f; unsigned u; } c; c.f = f;
  return (unsigned short)((c.u + 0x7fffu + ((c.u >> 16) & 1u)) >> 16);
}
__device__ __forceinline__ void load16_to_lds(const void* g, void* l) {
  __builtin_amdgcn_global_load_lds(
      (__attribute__((address_space(1))) void*)(void*)(unsigned long long)(const char*)g,
      (__attribute__((address_space(3))) void*)l, 16, 0, 0);
}

// ---------- dtype detection: is d_in data bf16 (1) or fp32 (0)? ----------
__global__ void detect_dtype(const unsigned* __restrict__ x, int* __restrict__ flag) {
  __shared__ int cnt;
  if (threadIdx.x == 0) cnt = 0;
  __syncthreads();
  unsigned w = x[((unsigned)threadIdx.x * 16381u) & ((1u << 21) - 1u)];
  unsigned lo = w & 0xFFFFu;
  int e = (int)((lo >> 7) & 0xFF);
  int plausible = (lo == 0u) || (e >= 100 && e <= 142);
  atomicAdd(&cnt, plausible);
  __syncthreads();
  if (threadIdx.x == 0) *flag = (cnt >= 192) ? 1 : 0;
}

// ---------- canonicalize any input to bf16 ----------
__global__ void conv_to_bf16(const void* __restrict__ src, unsigned short* __restrict__ dst,
                             int n, const int* __restrict__ flag) {
  int stride = gridDim.x * blockDim.x;
  int i0 = blockIdx.x * blockDim.x + threadIdx.x;
  if (*flag) {
    const unsigned short* s = (const unsigned short*)src;
    for (int i = i0; i < n; i += stride) dst[i] = s[i];
  } else {
    const float* s = (const float*)src;
    for (int i = i0; i < n; i += stride) dst[i] = f2bf(s[i]);
  }
}

// ---------- fused convert+transpose: in[K][N] (bf16 or fp32 per flag) -> out[N][K] bf16 ----------
__global__ __launch_bounds__(256) void transpose_conv(const void* __restrict__ in,
                                                      unsigned short* __restrict__ out,
                                                      int K, int N, const int* __restrict__ flag) {
  __shared__ unsigned short tile[32][33];
  int n0 = blockIdx.x * 32, k0 = blockIdx.y * 32;
  int tx = threadIdx.x, ty = threadIdx.y;   // (32,8)
  if (*flag) {
    const unsigned short* p = (const unsigned short*)in;
#pragma unroll
    for (int i = 0; i < 4; ++i)
      tile[ty + 8*i][tx] = p[(size_t)(k0 + ty + 8*i) * N + n0 + tx];
  } else {
    const float* p = (const float*)in;
#pragma unroll
    for (int i = 0; i < 4; ++i)
      tile[ty + 8*i][tx] = f2bf(p[(size_t)(k0 + ty + 8*i) * N + n0 + tx]);
  }
  __syncthreads();
#pragma unroll
  for (int i = 0; i < 4; ++i)
    out[(size_t)(n0 + ty + 8*i) * K + k0 + tx] = tile[tx][ty + 8*i];
}

// ---------- v4 GEMM core: m201 256x256 8-phase port (4 phases/K-tile, 2 K-tiles ~ 8 phases) ----
// BM=BN=256, BK=64, 8 waves (2M x 4N), wave-tile 128x64, acc[8][4].
// LDS: 2 dbufs x (A 256x64 + B 256x64) bf16 = 2 x 64 KiB = 128 KiB, 1 block/CU.
// Per K-tile: 4 quadrant phases, zigzag (mh0,nh0)->(mh0,nh1)->(mh1,nh1)->(mh1,nh0);
// A-half carried 2 phases in regs (8 frags), B-half carried 1 (4 frags) -> 28 ds_read/K-tile
// (12/4/8/4 per phase). Each phase: {ds_read subtile | stage ONE half-tile (2 gload_lds)
// into the half-slot freed last phase | s_barrier | lgkmcnt(0) | setprio(1) 16 MFMA
// setprio(0) | s_barrier}. Staging order: p0: Bh0(t+1); p1: Ah0(t+2); p2: Bh1(t+2);
// p3: Ah1(t+2). Boundary: vmcnt(6) (= 3 half-tiles in flight, m201's formula);
// ledger by induction: after boundary of iter t, outstanding = {Ah0,Bh1,Ah1}(t+2).
// Tail: t==NT-2 -> vmcnt(0). Swizzle (both-sides): 128B rows, phys chunk = c ^ (row&7);
// inverse on global source, forward on ds_read (family measured 0 conflicts R1-R3).
// A-half h = rows {64h..64h+63} u {128+64h..}; B-half h = rows with (row&63)>>5 == h.

__device__ __forceinline__ void gemm_core_v4(const unsigned short* __restrict__ Ag,
                                             const unsigned short* __restrict__ Btg,
                                             int m0, int n0,
                                             unsigned short* sm,
                                             f32x4 (&acc)[8][4]) {
  char* smb = (char*)sm;
  const int t = threadIdx.x;                 // 0..511
  const int lane = t & 63, w = t >> 6;       // 8 waves
  const int wr = w >> 2, wc = w & 3;         // 2M x 4N, wave tile 128x64
  const int frm = lane & 15, qd = lane >> 4;
  const int px0 = ((qd    ) ^ (frm & 7)) * 16;   // ks=0 swizzled chunk byte off
  const int px1 = ((4 + qd) ^ (frm & 7)) * 16;   // ks=1
  const int NT = ND / 64;                    // 16 K-tiles

  auto stageAh = [&](int kt, int h) {
    char* dst = smb + (kt & 1) * 65536;      // A region of dbuf
    int kk = kt * 64;
#pragma unroll
    for (int u = 0; u < 2; ++u) {
      int ci = u * 512 + t;
      int rp = ci >> 3;                      // 0..127
      int row = ((rp >> 6) * 128) + h * 64 + (rp & 63);
      int l = (ci & 7) ^ (row & 7);          // inverse-swizzled global chunk
      load16_to_lds(Ag + (size_t)(m0 + row) * ND + kk + l * 8,
                    dst + row * 128 + (ci & 7) * 16);
    }
  };
  auto stageBh = [&](int kt, int h) {
    char* dst = smb + (kt & 1) * 65536 + 32768;   // B region of dbuf
    int kk = kt * 64;
#pragma unroll
    for (int u = 0; u < 2; ++u) {
      int ci = u * 512 + t;
      int rp = ci >> 3;
      int row = ((rp >> 5) * 64) + h * 32 + (rp & 31);
      int l = (ci & 7) ^ (row & 7);
      load16_to_lds(Btg + (size_t)(n0 + row) * ND + kk + l * 8,
                    dst + row * 128 + (ci & 7) * 16);
    }
  };

  // prologue: tile0 all 4 halves; tile1 Ah0,Bh1,Ah1 (Bh0(1) staged at p0 of iter 0).
  stageAh(0, 0); stageAh(0, 1); stageBh(0, 0); stageBh(0, 1);
  stageAh(1, 0); stageBh(1, 1); stageAh(1, 1);
  asm volatile("s_waitcnt vmcnt(6)\n\ts_barrier" ::: "memory");   // tile 0 landed

  for (int kt = 0; kt < NT; ++kt) {
    const char* Ab = smb + (kt & 1) * 65536;
    const char* Bb = Ab + 32768;
    bf16x8 a[4][2], b[2][2];

    // ---- p0: quadrant (mh0, nh0); stage Bh0(kt+1) ----
#pragma unroll
    for (int i = 0; i < 4; ++i) {
      int row = 128*wr + 16*i + frm;
      a[i][0] = *(const bf16x8*)(Ab + row * 128 + px0);
      a[i][1] = *(const bf16x8*)(Ab + row * 128 + px1);
    }
#pragma unroll
    for (int j = 0; j < 2; ++j) {
      int row = 64*wc + 16*j + frm;
      b[j][0] = *(const bf16x8*)(Bb + row * 128 + px0);
      b[j][1] = *(const bf16x8*)(Bb + row * 128 + px1);
    }
    if (kt + 1 < NT) stageBh(kt + 1, 0);
    asm volatile("s_barrier" ::: "memory");
    asm volatile("s_waitcnt lgkmcnt(0)" ::: "memory");
    __builtin_amdgcn_s_setprio(1);
#pragma unroll
    for (int i = 0; i < 4; ++i)
#pragma unroll
      for (int j = 0; j < 2; ++j) {
        acc[i][j] = __builtin_amdgcn_mfma_f32_16x16x32_bf16(a[i][0], b[j][0], acc[i][j], 0, 0, 0);
        acc[i][j] = __builtin_amdgcn_mfma_f32_16x16x32_bf16(a[i][1], b[j][1], acc[i][j], 0, 0, 0);
      }
    __builtin_amdgcn_s_setprio(0);
    asm volatile("s_barrier" ::: "memory");

    // ---- p1: (mh0, nh1); reuse a; read B j=2,3; stage Ah0(kt+2) ----
#pragma unroll
    for (int j = 0; j < 2; ++j) {
      int row = 64*wc + 16*(2 + j) + frm;
      b[j][0] = *(const bf16x8*)(Bb + row * 128 + px0);
      b[j][1] = *(const bf16x8*)(Bb + row * 128 + px1);
    }
    if (kt + 2 < NT) stageAh(kt + 2, 0);
    asm volatile("s_barrier" ::: "memory");
    asm volatile("s_waitcnt lgkmcnt(0)" ::: "memory");
    __builtin_amdgcn_s_setprio(1);
#pragma unroll
    for (int i = 0; i < 4; ++i)
#pragma unroll
      for (int j = 0; j < 2; ++j) {
        acc[i][2+j] = __builtin_amdgcn_mfma_f32_16x16x32_bf16(a[i][0], b[j][0], acc[i][2+j], 0, 0, 0);
        acc[i][2+j] = __builtin_amdgcn_mfma_f32_16x16x32_bf16(a[i][1], b[j][1], acc[i][2+j], 0, 0, 0);
      }
    __builtin_amdgcn_s_setprio(0);
    asm volatile("s_barrier" ::: "memory");

    // ---- p2: (mh1, nh1); read A i=4..7; reuse b; stage Bh1(kt+2) ----
#pragma unroll
    for (int i = 0; i < 4; ++i) {
      int row = 128*wr + 16*(4 + i) + frm;
      a[i][0] = *(const bf16x8*)(Ab + row * 128 + px0);
      a[i][1] = *(const bf16x8*)(Ab + row * 128 + px1);
    }
    if (kt + 2 < NT) stageBh(kt + 2, 1);
    asm volatile("s_barrier" ::: "memory");
    asm volatile("s_waitcnt lgkmcnt(0)" ::: "memory");
    __builtin_amdgcn_s_setprio(1);
#pragma unroll
    for (int i = 0; i < 4; ++i)
#pragma unroll
      for (int j = 0; j < 2; ++j) {
        acc[4+i][2+j] = __builtin_amdgcn_mfma_f32_16x16x32_bf16(a[i][0], b[j][0], acc[4+i][2+j], 0, 0, 0);
        acc[4+i][2+j] = __builtin_amdgcn_mfma_f32_16x16x32_bf16(a[i][1], b[j][1], acc[4+i][2+j], 0, 0, 0);
      }
    __builtin_amdgcn_s_setprio(0);
    asm volatile("s_barrier" ::: "memory");

    // ---- p3: (mh1, nh0); reuse a; read B j=0,1 again; stage Ah1(kt+2) ----
#pragma unroll
    for (int j = 0; j < 2; ++j) {
      int row = 64*wc + 16*j + frm;
      b[j][0] = *(const bf16x8*)(Bb + row * 128 + px0);
      b[j][1] = *(const bf16x8*)(Bb + row * 128 + px1);
    }
    if (kt + 2 < NT) stageAh(kt + 2, 1);
    asm volatile("s_barrier" ::: "memory");
    asm volatile("s_waitcnt lgkmcnt(0)" ::: "memory");
    __builtin_amdgcn_s_setprio(1);
#pragma unroll
    for (int i = 0; i < 4; ++i)
#pragma unroll
      for (int j = 0; j < 2; ++j) {
        acc[4+i][j] = __builtin_amdgcn_mfma_f32_16x16x32_bf16(a[i][0], b[j][0], acc[4+i][j], 0, 0, 0);
        acc[4+i][j] = __builtin_amdgcn_mfma_f32_16x16x32_bf16(a[i][1], b[j][1], acc[4+i][j], 0, 0, 0);
      }
    __builtin_amdgcn_s_setprio(0);

    // K-tile boundary: tile kt+1 must be fully landed; keep 3 halves of kt+2 in flight.
    if (kt < NT - 2)       asm volatile("s_waitcnt vmcnt(6)\n\ts_barrier" ::: "memory");
    else if (kt == NT - 2) asm volatile("s_waitcnt vmcnt(0)\n\ts_barrier" ::: "memory");
    // kt == NT-1: fall through to epilogue (register-only)
  }
}

// ---------- QKV projection, v4 core; scatter q/k:(B,H,S,E), v:(B,H,E,S) ----------
__global__ __launch_bounds__(512, 1) void gemm_qkv_v4(const unsigned short* __restrict__ X,
                                                      const unsigned short* __restrict__ W1T,
                                                      const unsigned short* __restrict__ battn,
                                                      unsigned short* __restrict__ qb,
                                                      unsigned short* __restrict__ kb,
                                                      unsigned short* __restrict__ vb) {
  __shared__ unsigned short sm[2 * 2 * 256 * 64];    // 128 KiB
  // XCD bijective swizzle: 384 = 8*48; XCD k owns 4 m-panels x all 12 n-panels.
  int flat = blockIdx.x + 12 * blockIdx.y;
  int virt = (flat & 7) * 48 + (flat >> 3);
  const int n0 = (virt % 12) * 256;
  const int m0 = (virt / 12) * 256;

  f32x4 acc[8][4] = {};
  gemm_core_v4(X, W1T, m0, n0, sm, acc);

  const int t = threadIdx.x, lane = t & 63, w = t >> 6;
  const int wr = w >> 2, wc = w & 3;
  const int coln = lane & 15, rbase = (lane >> 4) * 4;
#pragma unroll
  for (int j = 0; j < 4; ++j) {
    int nn = n0 + 64*wc + 16*j + coln;       // 0..3071
    int qq = nn >> 10;                       // 0=q 1=k 2=v
    int h  = (nn >> 6) & 15;
    int e  = nn & 63;
    float bias = bf2f(battn[nn]);
    unsigned short* dst = (qq == 0) ? qb : ((qq == 1) ? kb : vb);
    float scale = (qq == 0) ? (0.125f * 1.44269504f) : 1.0f;
#pragma unroll
    for (int i = 0; i < 8; ++i) {
#pragma unroll
      for (int rr = 0; rr < 4; ++rr) {
        int mm = m0 + 128*wr + 16*i + rbase + rr;
        int bb = mm >> 11, s = mm & 2047;
        float v = (acc[i][j][rr] + bias) * scale;
        size_t idx;
        if (qq == 2) idx = (((size_t)bb * NH + h) * NE + e) * NS + s;   // V transposed
        else         idx = (((size_t)bb * NH + h) * NS + s) * NE + e;
        dst[idx] = f2bf(v);
      }
    }
  }
}

// ---------- output projection, v4 core; store dtype per flag ----------
__global__ __launch_bounds__(512, 1) void gemm_proj_v4(const unsigned short* __restrict__ A,
                                                       const unsigned short* __restrict__ W2T,
                                                       const unsigned short* __restrict__ bproj,
                                                       void* __restrict__ outv,
                                                       const int* __restrict__ flag) {
  __shared__ unsigned short sm[2 * 2 * 256 * 64];    // 128 KiB
  // 128 blocks = 0.5 round; XCD swizzle: 128 = 8*16.
  int flat = blockIdx.x + 4 * blockIdx.y;
  int virt = (flat & 7) * 16 + (flat >> 3);
  const int n0 = (virt & 3) * 256;
  const int m0 = (virt >> 2) * 256;

  f32x4 acc[8][4] = {};
  gemm_core_v4(A, W2T, m0, n0, sm, acc);

  const int isbf = *flag;
  unsigned short* out16 = (unsigned short*)outv;
  float* out32 = (float*)outv;
  const int t = threadIdx.x, lane = t & 63, w = t >> 6;
  const int wr = w >> 2, wc = w & 3;
  const int coln = lane & 15, rbase = (lane >> 4) * 4;
#pragma unroll
  for (int j = 0; j < 4; ++j) {
    int nn = n0 + 64*wc + 16*j + coln;
    float bias = bf2f(bproj[nn]);
#pragma unroll
    for (int i = 0; i < 8; ++i) {
#pragma unroll
      for (int rr = 0; rr < 4; ++rr) {
        int mm = m0 + 128*wr + 16*i + rbase + rr;
        float v = acc[i][j][rr] + bias;
        if (isbf) out16[(size_t)mm * ND + nn] = f2bf(v);
        else      out32[(size_t)mm * ND + nn] = v;
      }
    }
  }
}

// ---------- causal flash attention: 1024 fully-resident blocks, 4/CU ----------
// Block i -> (bh = i&63, qt = QTAB[(i>>6)&3][i>>8]); QTAB rows sum to 30 so the 4
// co-resident blocks per CU (i, i+256, ...) balance AND share bh (K/V L2 locality).
// 128 q-rows/block (wave w owns rows 32w..32w+31), 32-key tiles, dbuf DMA, vmcnt(2).
// LDS 32 KB: QPs 16K (Q then P, pitch-64hw octet-swizzled) + K dbuf 8K + V dbuf 8K.
// Vt layout: 32 rows x 128B; row r = e-pair (2r, 2r+1) x 32 keys, octet-swizzled.
__global__ __launch_bounds__(256, 4) void attn_causal(const unsigned short* __restrict__ qb,
                                                      const unsigned short* __restrict__ kb,
                                                      const unsigned short* __restrict__ vtb,
                                                      unsigned short* __restrict__ ob) {
  __shared__ unsigned short QPs[128 * 64];
  __shared__ unsigned short Ks[2][32 * 64];
  __shared__ unsigned short Vt[2][32 * 64];

  int t = threadIdx.x, lane = t & 63, w = t >> 6;
  int qd = lane >> 4, li = lane & 15;
  int sw0 = ((qd ^ (li & 7)) * 8);
  int sw1 = (((4 + qd) ^ (li & 7)) * 8);

  const int qtab[4][4] = {{15,8,7,0},{14,9,6,1},{13,10,5,2},{12,11,4,3}};
  int bi = blockIdx.x;
  int bh = bi & 63;
  int qt = qtab[(bi >> 6) & 3][bi >> 8];
  int q0 = qt * 128;
  int NT = 4 * qt + 4;                       // number of 32-key tiles
  size_t base = (size_t)bh * NS * NE;
  int bb = bh >> 4, hh = bh & 15;

  bf16x8 onesf;
#pragma unroll
  for (int j = 0; j < 8; ++j) onesf[j] = (__bf16)1.0f;

  auto stage_kv = [&](int kt, int buf) {
    int k0 = kt * 32;
    int r = t >> 3, p = t & 7, l = p ^ (r & 7);
    load16_to_lds(kb + base + (size_t)(k0 + r) * NE + l * 8, (char*)Ks[buf] + t * 16);
    int e = 2 * r + (l >> 2);
    load16_to_lds(vtb + base + (size_t)e * NS + k0 + (l & 3) * 8, (char*)Vt[buf] + t * 16);
  };

  // stage Q (128x64, swizzled) + first K/V tile
#pragma unroll
  for (int c = 0; c < 4; ++c) {
    int ch = c * 256 + t;
    int r = ch >> 3, jl = (ch & 7) ^ (r & 7);
    load16_to_lds(qb + base + (size_t)(q0 + r) * NE + jl * 8, (char*)QPs + ch * 16);
  }
  stage_kv(0, 0);
  asm volatile("s_waitcnt vmcnt(2)\n\ts_barrier" ::: "memory");  // Q drained, kv0 in flight

  bf16x8 qa[2][2];
#pragma unroll
  for (int i = 0; i < 2; ++i) {
    const unsigned short* qr = QPs + (32*w + 16*i + li) * 64;
    qa[i][0] = *(const bf16x8*)(qr + sw0);
    qa[i][1] = *(const bf16x8*)(qr + sw1);
  }

  f32x4 o[2][4] = {};
  float l_run[2][4] = {};

  for (int kt = 0; kt < NT; ++kt) {
    int cur = kt & 1;
    // all waves done with buf[cur^1] (and, at kt=0, with their qa reads)
    asm volatile("s_waitcnt lgkmcnt(0)\n\ts_barrier" ::: "memory");
    if (kt + 1 < NT) {
      stage_kv(kt + 1, cur ^ 1);
      asm volatile("s_waitcnt vmcnt(2)\n\ts_barrier" ::: "memory");  // drain tile kt only
    } else {
      asm volatile("s_waitcnt vmcnt(0)\n\ts_barrier" ::: "memory");
    }

    int k0 = kt * 32;
    const unsigned short* Ksc = Ks[cur];
    const unsigned short* Vtc = Vt[cur];

    bf16x8 kfr[2][2];
#pragma unroll
    for (int c = 0; c < 2; ++c) {
      const unsigned short* kr = Ksc + (16*c + li) * 64;
      kfr[c][0] = *(const bf16x8*)(kr + sw0);
      kfr[c][1] = *(const bf16x8*)(kr + sw1);
    }

    int need_mask = (k0 >= q0);
#pragma unroll
    for (int i = 0; i < 2; ++i) {
#pragma unroll
      for (int c = 0; c < 2; ++c) {
        f32x4 s = {};
        s = __builtin_amdgcn_mfma_f32_16x16x32_bf16(qa[i][0], kfr[c][0], s, 0, 0, 0);
        s = __builtin_amdgcn_mfma_f32_16x16x32_bf16(qa[i][1], kfr[c][1], s, 0, 0, 0);
#pragma unroll
        for (int rr = 0; rr < 4; ++rr) {
          float pv = exp2f(s[rr]);
          if (need_mask) {
            int colk = k0 + 16*c + li;
            int rowq = q0 + 32*w + 16*i + qd*4 + rr;
            if (colk > rowq) pv = 0.f;
          }
          int prow = 32*w + 16*i + qd*4 + rr;
          int lo = 2*c + (li >> 3);
          QPs[prow * 64 + ((lo ^ (prow & 7)) * 8) + (li & 7)] =
              (unsigned short)(__float_as_uint(pv) >> 16);
        }
      }
    }

    // read P as A-operand (wave-local rows; in-order LDS => no barrier)
    bf16x8 pa[2];
#pragma unroll
    for (int i = 0; i < 2; ++i)
      pa[i] = *(const bf16x8*)(QPs + (32*w + 16*i + li) * 64 + sw0);

    // row sums via ones-MFMA (k=32 covers the whole tile)
#pragma unroll
    for (int i = 0; i < 2; ++i) {
      f32x4 sm = {};
      sm = __builtin_amdgcn_mfma_f32_16x16x32_bf16(pa[i], onesf, sm, 0, 0, 0);
#pragma unroll
      for (int rr = 0; rr < 4; ++rr) l_run[i][rr] += sm[rr];
    }

    // O += P V : B-frag from packed Vt (row = e>>1, octet = (e&1)*4+qd, swizzled)
#pragma unroll
    for (int c2 = 0; c2 < 4; ++c2) {
      const unsigned short* vr = Vtc + (8*c2 + (li >> 1)) * 64;
      bf16x8 vf = *(const bf16x8*)(vr + ((((li & 1) * 4 + qd) ^ ((li >> 1) & 7)) * 8));
#pragma unroll
      for (int i = 0; i < 2; ++i)
        o[i][c2] = __builtin_amdgcn_mfma_f32_16x16x32_bf16(pa[i], vf, o[i][c2], 0, 0, 0);
    }
  }

  // write O to (B,S,H,E)
#pragma unroll
  for (int i = 0; i < 2; ++i)
#pragma unroll
    for (int c = 0; c < 4; ++c)
#pragma unroll
      for (int rr = 0; rr < 4; ++rr) {
        int rowm = 32*w + 16*i + qd*4 + rr;
        float inv = 1.0f / fmaxf(l_run[i][rr], 1e-30f);
        float ov = o[i][c][rr] * inv;
        int e = 16*c + li;
        ob[(((size_t)bb * NS + (q0 + rowm)) * NH + hh) * NE + e] = f2bf(ov);
      }
}

extern "C" void kernel_launch(void* const* d_in, const int* in_sizes, int n_in,
                              void* d_out, int out_size, void* d_ws, size_t ws_size,
                              hipStream_t stream) {
  (void)in_sizes; (void)n_in; (void)out_size; (void)ws_size;
  char* ws = (char*)d_ws;
  unsigned short* W1T = (unsigned short*)(ws);                       // 6,291,456
  unsigned short* W2T = (unsigned short*)(ws + 6291456);             // 2,097,152
  unsigned short* qb  = (unsigned short*)(ws + 8388608);             // 16 MB
  unsigned short* kb  = (unsigned short*)(ws + 25165824);            // 16 MB
  unsigned short* vb  = (unsigned short*)(ws + 41943040);            // 16 MB (B,H,E,S)
  unsigned short* ob  = (unsigned short*)(ws + 58720256);            // 16 MB
  unsigned short* bac = (unsigned short*)(ws + 75497472);            // 8 KB
  unsigned short* bpc = (unsigned short*)(ws + 75505664);            // 8 KB
  int*            flg = (int*)(ws + 75513856);
  unsigned short* xc  = ob;   // converted x, dead before ob written

  detect_dtype<<<1, 256, 0, stream>>>((const unsigned*)d_in[0], flg);
  conv_to_bf16<<<2048, 256, 0, stream>>>(d_in[0], xc,  NB*NS*ND, flg);
  conv_to_bf16<<<12,   256, 0, stream>>>(d_in[2], bac, 3*NH*NE, flg);
  conv_to_bf16<<<4,    256, 0, stream>>>(d_in[4], bpc, ND, flg);

  transpose_conv<<<dim3(3072/32, 1024/32), dim3(32, 8), 0, stream>>>(d_in[1], W1T, 1024, 3072, flg);
  transpose_conv<<<dim3(1024/32, 1024/32), dim3(32, 8), 0, stream>>>(d_in[3], W2T, 1024, 1024, flg);
  gemm_qkv_v4<<<dim3(3072/256, NM/256), 512, 0, stream>>>(xc, W1T, bac, qb, kb, vb);
  attn_causal<<<dim3(1024), 256, 0, stream>>>(qb, kb, vb, ob);
  gemm_proj_v4<<<dim3(1024/256, NM/256), 512, 0, stream>>>(ob, W2T, bpc, d_out, flg);
}

// Round 5
// 263.415 us; speedup vs baseline: 1.1733x; 1.1733x over previous
//
#include <hip/hip_runtime.h>

// Problem: B=4, S=2048, D=1024, H=16, HD=64.
#define NB 4
#define NS 2048
#define ND 1024
#define NH 16
#define NE 64
#define NM (NB*NS)   // 8192 rows

typedef __attribute__((ext_vector_type(8))) __bf16 bf16x8;           // MFMA A/B frag (4 VGPRs)
typedef __attribute__((ext_vector_type(4))) float f32x4;             // MFMA C/D frag

__device__ __forceinline__ float bf2f(unsigned short h) {
  union { unsigned u; float f; } c; c.u = ((unsigned)h) << 16; return c.f;
}
__device__ __forceinline__ unsigned short f2bf(float f) {
  union { float f; unsigned u; } c; c.f = f;
  return (unsigned short)((c.u + 0x7fffu + ((c.u >> 16) & 1u)) >> 16);
}
__device__ __forceinline__ void load16_to_lds(const void* g, void* l) {
  __builtin_amdgcn_global_load_lds(
      (__attribute__((address_space(1))) void*)(void*)(unsigned long long)(const char*)g,
      (__attribute__((address_space(3))) void*)l, 16, 0, 0);
}

// ---------- dtype detection: is d_in data bf16 (1) or fp32 (0)? ----------
__global__ void detect_dtype(const unsigned* __restrict__ x, int* __restrict__ flag) {
  __shared__ int cnt;
  if (threadIdx.x == 0) cnt = 0;
  __syncthreads();
  unsigned w = x[((unsigned)threadIdx.x * 16381u) & ((1u << 21) - 1u)];
  unsigned lo = w & 0xFFFFu;
  int e = (int)((lo >> 7) & 0xFF);
  int plausible = (lo == 0u) || (e >= 100 && e <= 142);
  atomicAdd(&cnt, plausible);
  __syncthreads();
  if (threadIdx.x == 0) *flag = (cnt >= 192) ? 1 : 0;
}

// ---------- canonicalize any input to bf16 ----------
__global__ void conv_to_bf16(const void* __restrict__ src, unsigned short* __restrict__ dst,
                             int n, const int* __restrict__ flag) {
  int stride = gridDim.x * blockDim.x;
  int i0 = blockIdx.x * blockDim.x + threadIdx.x;
  if (*flag) {
    const unsigned short* s = (const unsigned short*)src;
    for (int i = i0; i < n; i += stride) dst[i] = s[i];
  } else {
    const float* s = (const float*)src;
    for (int i = i0; i < n; i += stride) dst[i] = f2bf(s[i]);
  }
}

// ---------- fused convert+transpose: in[K][N] (bf16 or fp32 per flag) -> out[N][K] bf16 ----------
__global__ __launch_bounds__(256) void transpose_conv(const void* __restrict__ in,
                                                      unsigned short* __restrict__ out,
                                                      int K, int N, const int* __restrict__ flag) {
  __shared__ unsigned short tile[32][33];
  int n0 = blockIdx.x * 32, k0 = blockIdx.y * 32;
  int tx = threadIdx.x, ty = threadIdx.y;   // (32,8)
  if (*flag) {
    const unsigned short* p = (const unsigned short*)in;
#pragma unroll
    for (int i = 0; i < 4; ++i)
      tile[ty + 8*i][tx] = p[(size_t)(k0 + ty + 8*i) * N + n0 + tx];
  } else {
    const float* p = (const float*)in;
#pragma unroll
    for (int i = 0; i < 4; ++i)
      tile[ty + 8*i][tx] = f2bf(p[(size_t)(k0 + ty + 8*i) * N + n0 + tx]);
  }
  __syncthreads();
#pragma unroll
  for (int i = 0; i < 4; ++i)
    out[(size_t)(n0 + ty + 8*i) * K + k0 + tx] = tile[tx][ty + 8*i];
}

// ---------- v5 GEMM core: T3 minimum 2-phase recipe (guide-verified 622-682 TF class) ----
// BM=256, BN=128, BK=64, 8 waves (4M x 2N), wave-tile 64x64, acc[4][4].
// LDS: 2 dbufs x (A 256x64 + B 128x64) bf16 = 2 x 48 KiB = 96 KiB, 1 block/CU.
// Per K-tile (ONE phase, ONE barrier):
//   { stage(t+1) -> buf[cur^1]  (6 gload_lds/thread, in flight across everything)
//     16 ds_read_b128 from buf[cur]
//     lgkmcnt(0); setprio(1); 32 MFMA; setprio(0)
//     vmcnt(0); s_barrier }          // drain is cheap: loads had the whole body to land
// Correctness: reads of buf[cur] complete before the barrier (lgkm0 precedes it), so
// re-staging buf[cur] next iter is safe; vmcnt(0)+barrier => buf[cur^1] fully written.
// Swizzle (both-sides, verified 0 conflicts R1-R4): rows of 128B, 8x16B chunks,
// LDS chunk c holds global chunk c^(row&7); reader at frag-chunk q uses q^(row&7).
#define BUFB 49152            // bytes per buf: A 256*128 + B 128*128

__device__ __forceinline__ void gemm_core_v5(const unsigned short* __restrict__ Ag,
                                             const unsigned short* __restrict__ Btg,
                                             int m0, int n0,
                                             unsigned short* sm,
                                             f32x4 (&acc)[4][4]) {
  char* smb = (char*)sm;
  const int t = threadIdx.x;                 // 0..511
  const int lane = t & 63, w = t >> 6;       // 8 waves
  const int wr = w >> 1, wc = w & 1;         // 4M x 2N, wave tile 64x64
  const int frm = lane & 15, qd = lane >> 4;
  const int px0 = ((qd    ) ^ (frm & 7)) * 16;   // ks=0 swizzled chunk byte offset
  const int px1 = ((4 + qd) ^ (frm & 7)) * 16;   // ks=1
  const int NT = ND / 64;                    // 16 K-tiles

  auto stage = [&](int kt, int b) {
    char* Ab = smb + b * BUFB;
    char* Bb = Ab + 32768;
    int kk = kt * 64;
#pragma unroll
    for (int u = 0; u < 4; ++u) {            // A: 256x64 = 2048 chunks of 16B
      int ci = u * 512 + t;
      int row = ci >> 3, c = ci & 7, l = c ^ (row & 7);
      load16_to_lds(Ag + (size_t)(m0 + row) * ND + kk + l * 8, Ab + ci * 16);
    }
#pragma unroll
    for (int u = 0; u < 2; ++u) {            // B: 128x64 = 1024 chunks of 16B
      int ci = u * 512 + t;
      int row = ci >> 3, c = ci & 7, l = c ^ (row & 7);
      load16_to_lds(Btg + (size_t)(n0 + row) * ND + kk + l * 8, Bb + ci * 16);
    }
  };

  // prologue: stage tile 0 into buf 0, drain, barrier
  stage(0, 0);
  asm volatile("s_waitcnt vmcnt(0)\n\ts_barrier" ::: "memory");

  for (int kt = 0; kt < NT; ++kt) {
    const int cur = kt & 1;
    const char* Ab = smb + cur * BUFB;
    const char* Bb = Ab + 32768;

    if (kt + 1 < NT) stage(kt + 1, cur ^ 1);   // issue prefetch FIRST (stays in flight)

    bf16x8 a[4][2], b[4][2];
#pragma unroll
    for (int i = 0; i < 4; ++i) {
      int row = 64*wr + 16*i + frm;
      a[i][0] = *(const bf16x8*)(Ab + row * 128 + px0);
      a[i][1] = *(const bf16x8*)(Ab + row * 128 + px1);
    }
#pragma unroll
    for (int j = 0; j < 4; ++j) {
      int row = 64*wc + 16*j + frm;
      b[j][0] = *(const bf16x8*)(Bb + row * 128 + px0);
      b[j][1] = *(const bf16x8*)(Bb + row * 128 + px1);
    }
    asm volatile("s_waitcnt lgkmcnt(0)" ::: "memory");
    __builtin_amdgcn_s_setprio(1);
#pragma unroll
    for (int i = 0; i < 4; ++i)
#pragma unroll
      for (int j = 0; j < 4; ++j) {
        acc[i][j] = __builtin_amdgcn_mfma_f32_16x16x32_bf16(a[i][0], b[j][0], acc[i][j], 0, 0, 0);
        acc[i][j] = __builtin_amdgcn_mfma_f32_16x16x32_bf16(a[i][1], b[j][1], acc[i][j], 0, 0, 0);
      }
    __builtin_amdgcn_s_setprio(0);
    if (kt + 1 < NT)
      asm volatile("s_waitcnt vmcnt(0)\n\ts_barrier" ::: "memory");   // next tile ready
    // kt == NT-1: fall through to epilogue (register-only)
  }
}

// ---------- QKV projection, v5 core; scatter q/k:(B,H,S,E), v:(B,H,E,S) ----------
__global__ __launch_bounds__(512, 2) void gemm_qkv_v5(const unsigned short* __restrict__ X,
                                                      const unsigned short* __restrict__ W1T,
                                                      const unsigned short* __restrict__ battn,
                                                      unsigned short* __restrict__ qb,
                                                      unsigned short* __restrict__ kb,
                                                      unsigned short* __restrict__ vb) {
  __shared__ unsigned short sm[2 * 384 * 64];        // 96 KiB
  // XCD bijective swizzle: 768 = 8*96; XCD k owns 4 consecutive m-panels x all 24 n-panels.
  int flat = blockIdx.x + 24 * blockIdx.y;
  int virt = (flat & 7) * 96 + (flat >> 3);
  const int n0 = (virt % 24) * 128;
  const int m0 = (virt / 24) * 256;

  f32x4 acc[4][4] = {};
  gemm_core_v5(X, W1T, m0, n0, sm, acc);

  const int t = threadIdx.x, lane = t & 63, w = t >> 6;
  const int wr = w >> 1, wc = w & 1;
  const int coln = lane & 15, rbase = (lane >> 4) * 4;
#pragma unroll
  for (int j = 0; j < 4; ++j) {
    int nn = n0 + 64*wc + 16*j + coln;       // 0..3071
    int qq = nn >> 10;                       // 0=q 1=k 2=v
    int h  = (nn >> 6) & 15;
    int e  = nn & 63;
    float bias = bf2f(battn[nn]);
    float scale = (qq == 0) ? (0.125f * 1.44269504f) : 1.0f;
    if (qq == 2) {
      // V (B,H,E,S): 4 rr values are 4 consecutive s -> one 8B packed store (8B-aligned:
      // s0 = m0+64wr+16i+rbase is a multiple of 4, elements are 2B).
#pragma unroll
      for (int i = 0; i < 4; ++i) {
        int mm0 = m0 + 64*wr + 16*i + rbase;
        int bb = mm0 >> 11, s0 = mm0 & 2047;
        unsigned long long pk = 0;
#pragma unroll
        for (int rr = 0; rr < 4; ++rr) {
          float v = acc[i][j][rr] + bias;
          pk |= ((unsigned long long)f2bf(v)) << (16 * rr);
        }
        size_t idx = (((size_t)bb * NH + h) * NE + e) * NS + s0;
        *(unsigned long long*)(vb + idx) = pk;
      }
    } else {
      unsigned short* dst = (qq == 0) ? qb : kb;
#pragma unroll
      for (int i = 0; i < 4; ++i) {
#pragma unroll
        for (int rr = 0; rr < 4; ++rr) {
          int mm = m0 + 64*wr + 16*i + rbase + rr;
          int bb = mm >> 11, s = mm & 2047;
          float v = (acc[i][j][rr] + bias) * scale;
          dst[(((size_t)bb * NH + h) * NS + s) * NE + e] = f2bf(v);
        }
      }
    }
  }
}

// ---------- output projection, v5 core; store dtype per flag ----------
__global__ __launch_bounds__(512, 2) void gemm_proj_v5(const unsigned short* __restrict__ A,
                                                       const unsigned short* __restrict__ W2T,
                                                       const unsigned short* __restrict__ bproj,
                                                       void* __restrict__ outv,
                                                       const int* __restrict__ flag) {
  __shared__ unsigned short sm[2 * 384 * 64];        // 96 KiB
  // 256 blocks = exactly 1/CU; XCD swizzle: 256 = 8*32.
  int flat = blockIdx.x + 8 * blockIdx.y;
  int virt = (flat & 7) * 32 + (flat >> 3);
  const int n0 = (virt % 8) * 128;
  const int m0 = (virt / 8) * 256;

  f32x4 acc[4][4] = {};
  gemm_core_v5(A, W2T, m0, n0, sm, acc);

  const int isbf = *flag;
  unsigned short* out16 = (unsigned short*)outv;
  float* out32 = (float*)outv;
  const int t = threadIdx.x, lane = t & 63, w = t >> 6;
  const int wr = w >> 1, wc = w & 1;
  const int coln = lane & 15, rbase = (lane >> 4) * 4;
#pragma unroll
  for (int j = 0; j < 4; ++j) {
    int nn = n0 + 64*wc + 16*j + coln;
    float bias = bf2f(bproj[nn]);
#pragma unroll
    for (int i = 0; i < 4; ++i) {
#pragma unroll
      for (int rr = 0; rr < 4; ++rr) {
        int mm = m0 + 64*wr + 16*i + rbase + rr;
        float v = acc[i][j][rr] + bias;
        if (isbf) out16[(size_t)mm * ND + nn] = f2bf(v);
        else      out32[(size_t)mm * ND + nn] = v;
      }
    }
  }
}

// ---------- causal flash attention: 1024 fully-resident blocks, 4/CU ----------
// Block i -> (bh = i&63, qt = QTAB[(i>>6)&3][i>>8]); QTAB rows sum to 30 so the 4
// co-resident blocks per CU (i, i+256, ...) balance AND share bh (K/V L2 locality).
// 128 q-rows/block (wave w owns rows 32w..32w+31), 32-key tiles, dbuf DMA, vmcnt(2).
// LDS 32 KB: QPs 16K (Q then P, pitch-64hw octet-swizzled) + K dbuf 8K + V dbuf 8K.
// Vt layout: 32 rows x 128B; row r = e-pair (2r, 2r+1) x 32 keys, octet-swizzled.
__global__ __launch_bounds__(256, 4) void attn_causal(const unsigned short* __restrict__ qb,
                                                      const unsigned short* __restrict__ kb,
                                                      const unsigned short* __restrict__ vtb,
                                                      unsigned short* __restrict__ ob) {
  __shared__ unsigned short QPs[128 * 64];
  __shared__ unsigned short Ks[2][32 * 64];
  __shared__ unsigned short Vt[2][32 * 64];

  int t = threadIdx.x, lane = t & 63, w = t >> 6;
  int qd = lane >> 4, li = lane & 15;
  int sw0 = ((qd ^ (li & 7)) * 8);
  int sw1 = (((4 + qd) ^ (li & 7)) * 8);

  const int qtab[4][4] = {{15,8,7,0},{14,9,6,1},{13,10,5,2},{12,11,4,3}};
  int bi = blockIdx.x;
  int bh = bi & 63;
  int qt = qtab[(bi >> 6) & 3][bi >> 8];
  int q0 = qt * 128;
  int NT = 4 * qt + 4;                       // number of 32-key tiles
  size_t base = (size_t)bh * NS * NE;
  int bb = bh >> 4, hh = bh & 15;

  bf16x8 onesf;
#pragma unroll
  for (int j = 0; j < 8; ++j) onesf[j] = (__bf16)1.0f;

  auto stage_kv = [&](int kt, int buf) {
    int k0 = kt * 32;
    int r = t >> 3, p = t & 7, l = p ^ (r & 7);
    load16_to_lds(kb + base + (size_t)(k0 + r) * NE + l * 8, (char*)Ks[buf] + t * 16);
    int e = 2 * r + (l >> 2);
    load16_to_lds(vtb + base + (size_t)e * NS + k0 + (l & 3) * 8, (char*)Vt[buf] + t * 16);
  };

  // stage Q (128x64, swizzled) + first K/V tile
#pragma unroll
  for (int c = 0; c < 4; ++c) {
    int ch = c * 256 + t;
    int r = ch >> 3, jl = (ch & 7) ^ (r & 7);
    load16_to_lds(qb + base + (size_t)(q0 + r) * NE + jl * 8, (char*)QPs + ch * 16);
  }
  stage_kv(0, 0);
  asm volatile("s_waitcnt vmcnt(2)\n\ts_barrier" ::: "memory");  // Q drained, kv0 in flight

  bf16x8 qa[2][2];
#pragma unroll
  for (int i = 0; i < 2; ++i) {
    const unsigned short* qr = QPs + (32*w + 16*i + li) * 64;
    qa[i][0] = *(const bf16x8*)(qr + sw0);
    qa[i][1] = *(const bf16x8*)(qr + sw1);
  }

  f32x4 o[2][4] = {};
  float l_run[2][4] = {};

  for (int kt = 0; kt < NT; ++kt) {
    int cur = kt & 1;
    // all waves done with buf[cur^1] (and, at kt=0, with their qa reads)
    asm volatile("s_waitcnt lgkmcnt(0)\n\ts_barrier" ::: "memory");
    if (kt + 1 < NT) {
      stage_kv(kt + 1, cur ^ 1);
      asm volatile("s_waitcnt vmcnt(2)\n\ts_barrier" ::: "memory");  // drain tile kt only
    } else {
      asm volatile("s_waitcnt vmcnt(0)\n\ts_barrier" ::: "memory");
    }

    int k0 = kt * 32;
    const unsigned short* Ksc = Ks[cur];
    const unsigned short* Vtc = Vt[cur];

    bf16x8 kfr[2][2];
#pragma unroll
    for (int c = 0; c < 2; ++c) {
      const unsigned short* kr = Ksc + (16*c + li) * 64;
      kfr[c][0] = *(const bf16x8*)(kr + sw0);
      kfr[c][1] = *(const bf16x8*)(kr + sw1);
    }

    int need_mask = (k0 >= q0);
#pragma unroll
    for (int i = 0; i < 2; ++i) {
#pragma unroll
      for (int c = 0; c < 2; ++c) {
        f32x4 s = {};
        s = __builtin_amdgcn_mfma_f32_16x16x32_bf16(qa[i][0], kfr[c][0], s, 0, 0, 0);
        s = __builtin_amdgcn_mfma_f32_16x16x32_bf16(qa[i][1], kfr[c][1], s, 0, 0, 0);
#pragma unroll
        for (int rr = 0; rr < 4; ++rr) {
          float pv = exp2f(s[rr]);
          if (need_mask) {
            int colk = k0 + 16*c + li;
            int rowq = q0 + 32*w + 16*i + qd*4 + rr;
            if (colk > rowq) pv = 0.f;
          }
          int prow = 32*w + 16*i + qd*4 + rr;
          int lo = 2*c + (li >> 3);
          QPs[prow * 64 + ((lo ^ (prow & 7)) * 8) + (li & 7)] =
              (unsigned short)(__float_as_uint(pv) >> 16);
        }
      }
    }

    // read P as A-operand (wave-local rows; in-order LDS => no barrier)
    bf16x8 pa[2];
#pragma unroll
    for (int i = 0; i < 2; ++i)
      pa[i] = *(const bf16x8*)(QPs + (32*w + 16*i + li) * 64 + sw0);

    // row sums via ones-MFMA (k=32 covers the whole tile)
#pragma unroll
    for (int i = 0; i < 2; ++i) {
      f32x4 sm = {};
      sm = __builtin_amdgcn_mfma_f32_16x16x32_bf16(pa[i], onesf, sm, 0, 0, 0);
#pragma unroll
      for (int rr = 0; rr < 4; ++rr) l_run[i][rr] += sm[rr];
    }

    // O += P V : B-frag from packed Vt (row = e>>1, octet = (e&1)*4+qd, swizzled)
#pragma unroll
    for (int c2 = 0; c2 < 4; ++c2) {
      const unsigned short* vr = Vtc + (8*c2 + (li >> 1)) * 64;
      bf16x8 vf = *(const bf16x8*)(vr + ((((li & 1) * 4 + qd) ^ ((li >> 1) & 7)) * 8));
#pragma unroll
      for (int i = 0; i < 2; ++i)
        o[i][c2] = __builtin_amdgcn_mfma_f32_16x16x32_bf16(pa[i], vf, o[i][c2], 0, 0, 0);
    }
  }

  // write O to (B,S,H,E)
#pragma unroll
  for (int i = 0; i < 2; ++i)
#pragma unroll
    for (int c = 0; c < 4; ++c)
#pragma unroll
      for (int rr = 0; rr < 4; ++rr) {
        int rowm = 32*w + 16*i + qd*4 + rr;
        float inv = 1.0f / fmaxf(l_run[i][rr], 1e-30f);
        float ov = o[i][c][rr] * inv;
        int e = 16*c + li;
        ob[(((size_t)bb * NS + (q0 + rowm)) * NH + hh) * NE + e] = f2bf(ov);
      }
}

extern "C" void kernel_launch(void* const* d_in, const int* in_sizes, int n_in,
                              void* d_out, int out_size, void* d_ws, size_t ws_size,
                              hipStream_t stream) {
  (void)in_sizes; (void)n_in; (void)out_size; (void)ws_size;
  char* ws = (char*)d_ws;
  unsigned short* W1T = (unsigned short*)(ws);                       // 6,291,456
  unsigned short* W2T = (unsigned short*)(ws + 6291456);             // 2,097,152
  unsigned short* qb  = (unsigned short*)(ws + 8388608);             // 16 MB
  unsigned short* kb  = (unsigned short*)(ws + 25165824);            // 16 MB
  unsigned short* vb  = (unsigned short*)(ws + 41943040);            // 16 MB (B,H,E,S)
  unsigned short* ob  = (unsigned short*)(ws + 58720256);            // 16 MB
  unsigned short* bac = (unsigned short*)(ws + 75497472);            // 8 KB
  unsigned short* bpc = (unsigned short*)(ws + 75505664);            // 8 KB
  int*            flg = (int*)(ws + 75513856);
  unsigned short* xc  = ob;   // converted x, dead before ob written

  detect_dtype<<<1, 256, 0, stream>>>((const unsigned*)d_in[0], flg);
  conv_to_bf16<<<2048, 256, 0, stream>>>(d_in[0], xc,  NB*NS*ND, flg);
  conv_to_bf16<<<12,   256, 0, stream>>>(d_in[2], bac, 3*NH*NE, flg);
  conv_to_bf16<<<4,    256, 0, stream>>>(d_in[4], bpc, ND, flg);

  transpose_conv<<<dim3(3072/32, 1024/32), dim3(32, 8), 0, stream>>>(d_in[1], W1T, 1024, 3072, flg);
  transpose_conv<<<dim3(1024/32, 1024/32), dim3(32, 8), 0, stream>>>(d_in[3], W2T, 1024, 1024, flg);
  gemm_qkv_v5<<<dim3(3072/128, NM/256), 512, 0, stream>>>(xc, W1T, bac, qb, kb, vb);
  attn_causal<<<dim3(1024), 256, 0, stream>>>(qb, kb, vb, ob);
  gemm_proj_v5<<<dim3(1024/128, NM/256), 512, 0, stream>>>(ob, W2T, bpc, d_out, flg);
}

// Round 6
// 262.548 us; speedup vs baseline: 1.1771x; 1.0033x over previous
//
#include <hip/hip_runtime.h>

// Problem: B=4, S=2048, D=1024, H=16, HD=64.
#define NB 4
#define NS 2048
#define ND 1024
#define NH 16
#define NE 64
#define NM (NB*NS)   // 8192 rows

typedef __attribute__((ext_vector_type(8))) __bf16 bf16x8;           // MFMA A/B frag (4 VGPRs)
typedef __attribute__((ext_vector_type(4))) float f32x4;             // MFMA C/D frag

__device__ __forceinline__ float bf2f(unsigned short h) {
  union { unsigned u; float f; } c; c.u = ((unsigned)h) << 16; return c.f;
}
__device__ __forceinline__ unsigned short f2bf(float f) {
  union { float f; unsigned u; } c; c.f = f;
  return (unsigned short)((c.u + 0x7fffu + ((c.u >> 16) & 1u)) >> 16);
}
__device__ __forceinline__ void load16_to_lds(const void* g, void* l) {
  __builtin_amdgcn_global_load_lds(
      (__attribute__((address_space(1))) void*)(void*)(unsigned long long)(const char*)g,
      (__attribute__((address_space(3))) void*)l, 16, 0, 0);
}

// ---------- dtype detection: is d_in data bf16 (1) or fp32 (0)? ----------
__global__ void detect_dtype(const unsigned* __restrict__ x, int* __restrict__ flag) {
  __shared__ int cnt;
  if (threadIdx.x == 0) cnt = 0;
  __syncthreads();
  unsigned w = x[((unsigned)threadIdx.x * 16381u) & ((1u << 21) - 1u)];
  unsigned lo = w & 0xFFFFu;
  int e = (int)((lo >> 7) & 0xFF);
  int plausible = (lo == 0u) || (e >= 100 && e <= 142);
  atomicAdd(&cnt, plausible);
  __syncthreads();
  if (threadIdx.x == 0) *flag = (cnt >= 192) ? 1 : 0;
}

// ---------- canonicalize any input to bf16 ----------
__global__ void conv_to_bf16(const void* __restrict__ src, unsigned short* __restrict__ dst,
                             int n, const int* __restrict__ flag) {
  int stride = gridDim.x * blockDim.x;
  int i0 = blockIdx.x * blockDim.x + threadIdx.x;
  if (*flag) {
    const unsigned short* s = (const unsigned short*)src;
    for (int i = i0; i < n; i += stride) dst[i] = s[i];
  } else {
    const float* s = (const float*)src;
    for (int i = i0; i < n; i += stride) dst[i] = f2bf(s[i]);
  }
}

// ---------- fused convert+transpose: in[K][N] (bf16 or fp32 per flag) -> out[N][K] bf16 ----------
__global__ __launch_bounds__(256) void transpose_conv(const void* __restrict__ in,
                                                      unsigned short* __restrict__ out,
                                                      int K, int N, const int* __restrict__ flag) {
  __shared__ unsigned short tile[32][33];
  int n0 = blockIdx.x * 32, k0 = blockIdx.y * 32;
  int tx = threadIdx.x, ty = threadIdx.y;   // (32,8)
  if (*flag) {
    const unsigned short* p = (const unsigned short*)in;
#pragma unroll
    for (int i = 0; i < 4; ++i)
      tile[ty + 8*i][tx] = p[(size_t)(k0 + ty + 8*i) * N + n0 + tx];
  } else {
    const float* p = (const float*)in;
#pragma unroll
    for (int i = 0; i < 4; ++i)
      tile[ty + 8*i][tx] = f2bf(p[(size_t)(k0 + ty + 8*i) * N + n0 + tx]);
  }
  __syncthreads();
#pragma unroll
  for (int i = 0; i < 4; ++i)
    out[(size_t)(n0 + ty + 8*i) * K + k0 + tx] = tile[tx][ty + 8*i];
}

// ---------- v5 GEMM core: T3 minimum 2-phase recipe (guide-verified 622-682 TF class) ----
// BM=256, BN=128, BK=64, 8 waves (4M x 2N), wave-tile 64x64, acc[4][4].
// LDS: 2 dbufs x (A 256x64 + B 128x64) bf16 = 2 x 48 KiB = 96 KiB, 1 block/CU.
// Per K-tile (ONE phase, ONE barrier):
//   { stage(t+1) -> buf[cur^1]; 16 ds_read_b128 from buf[cur];
//     lgkmcnt(0); setprio(1); 32 MFMA; setprio(0); vmcnt(0); s_barrier }
#define BUFB 49152            // bytes per buf: A 256*128 + B 128*128

__device__ __forceinline__ void gemm_core_v5(const unsigned short* __restrict__ Ag,
                                             const unsigned short* __restrict__ Btg,
                                             int m0, int n0,
                                             unsigned short* sm,
                                             f32x4 (&acc)[4][4]) {
  char* smb = (char*)sm;
  const int t = threadIdx.x;                 // 0..511
  const int lane = t & 63, w = t >> 6;       // 8 waves
  const int wr = w >> 1, wc = w & 1;         // 4M x 2N, wave tile 64x64
  const int frm = lane & 15, qd = lane >> 4;
  const int px0 = ((qd    ) ^ (frm & 7)) * 16;   // ks=0 swizzled chunk byte offset
  const int px1 = ((4 + qd) ^ (frm & 7)) * 16;   // ks=1
  const int NT = ND / 64;                    // 16 K-tiles

  auto stage = [&](int kt, int b) {
    char* Ab = smb + b * BUFB;
    char* Bb = Ab + 32768;
    int kk = kt * 64;
#pragma unroll
    for (int u = 0; u < 4; ++u) {            // A: 256x64 = 2048 chunks of 16B
      int ci = u * 512 + t;
      int row = ci >> 3, c = ci & 7, l = c ^ (row & 7);
      load16_to_lds(Ag + (size_t)(m0 + row) * ND + kk + l * 8, Ab + ci * 16);
    }
#pragma unroll
    for (int u = 0; u < 2; ++u) {            // B: 128x64 = 1024 chunks of 16B
      int ci = u * 512 + t;
      int row = ci >> 3, c = ci & 7, l = c ^ (row & 7);
      load16_to_lds(Btg + (size_t)(n0 + row) * ND + kk + l * 8, Bb + ci * 16);
    }
  };

  // prologue: stage tile 0 into buf 0, drain, barrier
  stage(0, 0);
  asm volatile("s_waitcnt vmcnt(0)\n\ts_barrier" ::: "memory");

  for (int kt = 0; kt < NT; ++kt) {
    const int cur = kt & 1;
    const char* Ab = smb + cur * BUFB;
    const char* Bb = Ab + 32768;

    if (kt + 1 < NT) stage(kt + 1, cur ^ 1);   // issue prefetch FIRST (stays in flight)

    bf16x8 a[4][2], b[4][2];
#pragma unroll
    for (int i = 0; i < 4; ++i) {
      int row = 64*wr + 16*i + frm;
      a[i][0] = *(const bf16x8*)(Ab + row * 128 + px0);
      a[i][1] = *(const bf16x8*)(Ab + row * 128 + px1);
    }
#pragma unroll
    for (int j = 0; j < 4; ++j) {
      int row = 64*wc + 16*j + frm;
      b[j][0] = *(const bf16x8*)(Bb + row * 128 + px0);
      b[j][1] = *(const bf16x8*)(Bb + row * 128 + px1);
    }
    asm volatile("s_waitcnt lgkmcnt(0)" ::: "memory");
    __builtin_amdgcn_s_setprio(1);
#pragma unroll
    for (int i = 0; i < 4; ++i)
#pragma unroll
      for (int j = 0; j < 4; ++j) {
        acc[i][j] = __builtin_amdgcn_mfma_f32_16x16x32_bf16(a[i][0], b[j][0], acc[i][j], 0, 0, 0);
        acc[i][j] = __builtin_amdgcn_mfma_f32_16x16x32_bf16(a[i][1], b[j][1], acc[i][j], 0, 0, 0);
      }
    __builtin_amdgcn_s_setprio(0);
    if (kt + 1 < NT)
      asm volatile("s_waitcnt vmcnt(0)\n\ts_barrier" ::: "memory");   // next tile ready
    // kt == NT-1: fall through to epilogue (register-only)
  }
}

// ---------- QKV projection, v5 core; scatter q/k:(B,H,S,E), v:(B,H,E,S) ----------
__global__ __launch_bounds__(512, 2) void gemm_qkv_v5(const unsigned short* __restrict__ X,
                                                      const unsigned short* __restrict__ W1T,
                                                      const unsigned short* __restrict__ battn,
                                                      unsigned short* __restrict__ qb,
                                                      unsigned short* __restrict__ kb,
                                                      unsigned short* __restrict__ vb) {
  __shared__ unsigned short sm[2 * 384 * 64];        // 96 KiB
  // XCD bijective swizzle: 768 = 8*96; XCD k owns 4 consecutive m-panels x all 24 n-panels.
  int flat = blockIdx.x + 24 * blockIdx.y;
  int virt = (flat & 7) * 96 + (flat >> 3);
  const int n0 = (virt % 24) * 128;
  const int m0 = (virt / 24) * 256;

  f32x4 acc[4][4] = {};
  gemm_core_v5(X, W1T, m0, n0, sm, acc);

  const int t = threadIdx.x, lane = t & 63, w = t >> 6;
  const int wr = w >> 1, wc = w & 1;
  const int coln = lane & 15, rbase = (lane >> 4) * 4;
#pragma unroll
  for (int j = 0; j < 4; ++j) {
    int nn = n0 + 64*wc + 16*j + coln;       // 0..3071
    int qq = nn >> 10;                       // 0=q 1=k 2=v
    int h  = (nn >> 6) & 15;
    int e  = nn & 63;
    float bias = bf2f(battn[nn]);
    float scale = (qq == 0) ? (0.125f * 1.44269504f) : 1.0f;
    if (qq == 2) {
      // V (B,H,E,S): 4 rr values are 4 consecutive s -> one 8B packed store
#pragma unroll
      for (int i = 0; i < 4; ++i) {
        int mm0 = m0 + 64*wr + 16*i + rbase;
        int bb = mm0 >> 11, s0 = mm0 & 2047;
        unsigned long long pk = 0;
#pragma unroll
        for (int rr = 0; rr < 4; ++rr) {
          float v = acc[i][j][rr] + bias;
          pk |= ((unsigned long long)f2bf(v)) << (16 * rr);
        }
        size_t idx = (((size_t)bb * NH + h) * NE + e) * NS + s0;
        *(unsigned long long*)(vb + idx) = pk;
      }
    } else {
      unsigned short* dst = (qq == 0) ? qb : kb;
#pragma unroll
      for (int i = 0; i < 4; ++i) {
#pragma unroll
        for (int rr = 0; rr < 4; ++rr) {
          int mm = m0 + 64*wr + 16*i + rbase + rr;
          int bb = mm >> 11, s = mm & 2047;
          float v = (acc[i][j][rr] + bias) * scale;
          dst[(((size_t)bb * NH + h) * NS + s) * NE + e] = f2bf(v);
        }
      }
    }
  }
}

// ---------- output projection, v5 core; store dtype per flag ----------
__global__ __launch_bounds__(512, 2) void gemm_proj_v5(const unsigned short* __restrict__ A,
                                                       const unsigned short* __restrict__ W2T,
                                                       const unsigned short* __restrict__ bproj,
                                                       void* __restrict__ outv,
                                                       const int* __restrict__ flag) {
  __shared__ unsigned short sm[2 * 384 * 64];        // 96 KiB
  // 256 blocks = exactly 1/CU; XCD swizzle: 256 = 8*32.
  int flat = blockIdx.x + 8 * blockIdx.y;
  int virt = (flat & 7) * 32 + (flat >> 3);
  const int n0 = (virt % 8) * 128;
  const int m0 = (virt / 8) * 256;

  f32x4 acc[4][4] = {};
  gemm_core_v5(A, W2T, m0, n0, sm, acc);

  const int isbf = *flag;
  unsigned short* out16 = (unsigned short*)outv;
  float* out32 = (float*)outv;
  const int t = threadIdx.x, lane = t & 63, w = t >> 6;
  const int wr = w >> 1, wc = w & 1;
  const int coln = lane & 15, rbase = (lane >> 4) * 4;
#pragma unroll
  for (int j = 0; j < 4; ++j) {
    int nn = n0 + 64*wc + 16*j + coln;
    float bias = bf2f(bproj[nn]);
#pragma unroll
    for (int i = 0; i < 4; ++i) {
#pragma unroll
      for (int rr = 0; rr < 4; ++rr) {
        int mm = m0 + 64*wr + 16*i + rbase + rr;
        float v = acc[i][j][rr] + bias;
        if (isbf) out16[(size_t)mm * ND + nn] = f2bf(v);
        else      out32[(size_t)mm * ND + nn] = v;
      }
    }
  }
}

// ---------- causal flash attention: 1024 fully-resident blocks, 4/CU ----------
// R6 VALU-cut edition (VALUBusy was 55% vs MfmaUtil 20%):
// (1) 16 P-store LDS byte-offsets precomputed ONCE and pinned in VGPRs (asm "+v") --
//     removes ~56 VALU/tile of rematerialized address math (VGPR was only 60).
// (2) row-sums accumulate IN the ones-MFMA C operand (lacc = mfma(pa,1,lacc)) --
//     removes per-tile zero-init + 8 v_add.
// (3) stage_kv uses induction pointers (+4096B / +64B per tile) instead of full
//     address re-derivation.
// Structure/layout byte-identical to the R5-verified kernel otherwise.
__global__ __launch_bounds__(256, 4) void attn_causal(const unsigned short* __restrict__ qb,
                                                      const unsigned short* __restrict__ kb,
                                                      const unsigned short* __restrict__ vtb,
                                                      unsigned short* __restrict__ ob) {
  __shared__ unsigned short QPs[128 * 64];
  __shared__ unsigned short Ks[2][32 * 64];
  __shared__ unsigned short Vt[2][32 * 64];

  int t = threadIdx.x, lane = t & 63, w = t >> 6;
  int qd = lane >> 4, li = lane & 15;
  int sw0 = ((qd ^ (li & 7)) * 8);
  int sw1 = (((4 + qd) ^ (li & 7)) * 8);

  const int qtab[4][4] = {{15,8,7,0},{14,9,6,1},{13,10,5,2},{12,11,4,3}};
  int bi = blockIdx.x;
  int bh = bi & 63;
  int qt = qtab[(bi >> 6) & 3][bi >> 8];
  int q0 = qt * 128;
  int NT = 4 * qt + 4;                       // number of 32-key tiles
  size_t base = (size_t)bh * NS * NE;
  int bb = bh >> 4, hh = bh & 15;

  bf16x8 onesf;
#pragma unroll
  for (int j = 0; j < 8; ++j) onesf[j] = (__bf16)1.0f;

  // (1) P-store byte offsets: fully loop-invariant; compute once, pin in VGPRs.
  unsigned pofs[2][2][4];
#pragma unroll
  for (int i = 0; i < 2; ++i)
#pragma unroll
    for (int c = 0; c < 2; ++c)
#pragma unroll
      for (int rr = 0; rr < 4; ++rr) {
        int prow = 32*w + 16*i + qd*4 + rr;
        int lo = 2*c + (li >> 3);
        pofs[i][c][rr] = (unsigned)((prow * 64 + ((lo ^ (prow & 7)) * 8) + (li & 7)) * 2);
        asm volatile("" : "+v"(pofs[i][c][rr]));
      }

  // (3) stage_kv induction pointers (advance by one 32-key tile per call)
  {
    // moved into lambda captures below
  }
  int r8 = t >> 3, p8 = t & 7, lsw = p8 ^ (r8 & 7);
  const char* ksrc = (const char*)(kb + base + (size_t)r8 * NE + lsw * 8);
  int ve = 2 * r8 + (lsw >> 2);
  const char* vsrc = (const char*)(vtb + base + (size_t)ve * NS + (lsw & 3) * 8);
  char* kdst = (char*)Ks[0] + t * 16;        // buf stride 4096 B
  char* vdst = (char*)Vt[0] + t * 16;

  auto stage_kv = [&](int buf) {             // stages the NEXT sequential tile
    load16_to_lds(ksrc, kdst + buf * 4096);
    load16_to_lds(vsrc, vdst + buf * 4096);
    ksrc += 32 * NE * 2;                     // +4096 B: next 32 keys (rows)
    vsrc += 32 * 2;                          // +64 B: next 32 keys (cols of Vt)
  };

  // stage Q (128x64, swizzled) + first K/V tile
#pragma unroll
  for (int c = 0; c < 4; ++c) {
    int ch = c * 256 + t;
    int r = ch >> 3, jl = (ch & 7) ^ (r & 7);
    load16_to_lds(qb + base + (size_t)(q0 + r) * NE + jl * 8, (char*)QPs + ch * 16);
  }
  stage_kv(0);
  asm volatile("s_waitcnt vmcnt(2)\n\ts_barrier" ::: "memory");  // Q drained, kv0 in flight

  bf16x8 qa[2][2];
#pragma unroll
  for (int i = 0; i < 2; ++i) {
    const unsigned short* qr = QPs + (32*w + 16*i + li) * 64;
    qa[i][0] = *(const bf16x8*)(qr + sw0);
    qa[i][1] = *(const bf16x8*)(qr + sw1);
  }

  f32x4 o[2][4] = {};
  f32x4 lacc[2] = {};                        // (2) row sums accumulated by MFMA C-in

  for (int kt = 0; kt < NT; ++kt) {
    int cur = kt & 1;
    // all waves done with buf[cur^1] (and, at kt=0, with their qa reads)
    asm volatile("s_waitcnt lgkmcnt(0)\n\ts_barrier" ::: "memory");
    if (kt + 1 < NT) {
      stage_kv(cur ^ 1);
      asm volatile("s_waitcnt vmcnt(2)\n\ts_barrier" ::: "memory");  // drain tile kt only
    } else {
      asm volatile("s_waitcnt vmcnt(0)\n\ts_barrier" ::: "memory");
    }

    int k0 = kt * 32;
    const unsigned short* Ksc = Ks[cur];
    const unsigned short* Vtc = Vt[cur];

    bf16x8 kfr[2][2];
#pragma unroll
    for (int c = 0; c < 2; ++c) {
      const unsigned short* kr = Ksc + (16*c + li) * 64;
      kfr[c][0] = *(const bf16x8*)(kr + sw0);
      kfr[c][1] = *(const bf16x8*)(kr + sw1);
    }

    int need_mask = (k0 >= q0);
#pragma unroll
    for (int i = 0; i < 2; ++i) {
#pragma unroll
      for (int c = 0; c < 2; ++c) {
        f32x4 s = {};
        s = __builtin_amdgcn_mfma_f32_16x16x32_bf16(qa[i][0], kfr[c][0], s, 0, 0, 0);
        s = __builtin_amdgcn_mfma_f32_16x16x32_bf16(qa[i][1], kfr[c][1], s, 0, 0, 0);
#pragma unroll
        for (int rr = 0; rr < 4; ++rr) {
          float pv = exp2f(s[rr]);
          if (need_mask) {
            int colk = k0 + 16*c + li;
            int rowq = q0 + 32*w + 16*i + qd*4 + rr;
            if (colk > rowq) pv = 0.f;
          }
          *(unsigned short*)((char*)QPs + pofs[i][c][rr]) =
              (unsigned short)(__float_as_uint(pv) >> 16);
        }
      }
    }

    // read P as A-operand (wave-local rows; in-order LDS => no barrier)
    bf16x8 pa[2];
#pragma unroll
    for (int i = 0; i < 2; ++i)
      pa[i] = *(const bf16x8*)(QPs + (32*w + 16*i + li) * 64 + sw0);

    // row sums via ones-MFMA, accumulated directly into lacc (C-in == C-out)
#pragma unroll
    for (int i = 0; i < 2; ++i)
      lacc[i] = __builtin_amdgcn_mfma_f32_16x16x32_bf16(pa[i], onesf, lacc[i], 0, 0, 0);

    // O += P V : B-frag from packed Vt (row = e>>1, octet = (e&1)*4+qd, swizzled)
#pragma unroll
    for (int c2 = 0; c2 < 4; ++c2) {
      const unsigned short* vr = Vtc + (8*c2 + (li >> 1)) * 64;
      bf16x8 vf = *(const bf16x8*)(vr + ((((li & 1) * 4 + qd) ^ ((li >> 1) & 7)) * 8));
#pragma unroll
      for (int i = 0; i < 2; ++i)
        o[i][c2] = __builtin_amdgcn_mfma_f32_16x16x32_bf16(pa[i], vf, o[i][c2], 0, 0, 0);
    }
  }

  // write O to (B,S,H,E)
#pragma unroll
  for (int i = 0; i < 2; ++i)
#pragma unroll
    for (int c = 0; c < 4; ++c)
#pragma unroll
      for (int rr = 0; rr < 4; ++rr) {
        int rowm = 32*w + 16*i + qd*4 + rr;
        float inv = 1.0f / fmaxf(lacc[i][rr], 1e-30f);
        float ov = o[i][c][rr] * inv;
        int e = 16*c + li;
        ob[(((size_t)bb * NS + (q0 + rowm)) * NH + hh) * NE + e] = f2bf(ov);
      }
}

extern "C" void kernel_launch(void* const* d_in, const int* in_sizes, int n_in,
                              void* d_out, int out_size, void* d_ws, size_t ws_size,
                              hipStream_t stream) {
  (void)in_sizes; (void)n_in; (void)out_size; (void)ws_size;
  char* ws = (char*)d_ws;
  unsigned short* W1T = (unsigned short*)(ws);                       // 6,291,456
  unsigned short* W2T = (unsigned short*)(ws + 6291456);             // 2,097,152
  unsigned short* qb  = (unsigned short*)(ws + 8388608);             // 16 MB
  unsigned short* kb  = (unsigned short*)(ws + 25165824);            // 16 MB
  unsigned short* vb  = (unsigned short*)(ws + 41943040);            // 16 MB (B,H,E,S)
  unsigned short* ob  = (unsigned short*)(ws + 58720256);            // 16 MB
  unsigned short* bac = (unsigned short*)(ws + 75497472);            // 8 KB
  unsigned short* bpc = (unsigned short*)(ws + 75505664);            // 8 KB
  int*            flg = (int*)(ws + 75513856);
  unsigned short* xc  = ob;   // converted x, dead before ob written

  detect_dtype<<<1, 256, 0, stream>>>((const unsigned*)d_in[0], flg);
  conv_to_bf16<<<2048, 256, 0, stream>>>(d_in[0], xc,  NB*NS*ND, flg);
  conv_to_bf16<<<12,   256, 0, stream>>>(d_in[2], bac, 3*NH*NE, flg);
  conv_to_bf16<<<4,    256, 0, stream>>>(d_in[4], bpc, ND, flg);

  transpose_conv<<<dim3(3072/32, 1024/32), dim3(32, 8), 0, stream>>>(d_in[1], W1T, 1024, 3072, flg);
  transpose_conv<<<dim3(1024/32, 1024/32), dim3(32, 8), 0, stream>>>(d_in[3], W2T, 1024, 1024, flg);
  gemm_qkv_v5<<<dim3(3072/128, NM/256), 512, 0, stream>>>(xc, W1T, bac, qb, kb, vb);
  attn_causal<<<dim3(1024), 256, 0, stream>>>(qb, kb, vb, ob);
  gemm_proj_v5<<<dim3(1024/128, NM/256), 512, 0, stream>>>(ob, W2T, bpc, d_out, flg);
}